// Round 12
// baseline (3899.611 us; speedup 1.0000x reference)
//
#include <hip/hip_runtime.h>
#include <math.h>

// Model dims (fixed by the reference)
#define T_DIM 512
#define B_DIM 64
#define J_DIM 256
#define H_DIM 256
#define K_TAP 25
#define NL    3
#define M_DIM (T_DIM*B_DIM)   // 32768 rows = (t,b)
#define NBH   (B_DIM*H_DIM)   // 16384
#define GUARD_ROWS 1536                  // 64*24 zero rows before row 0
#define GUARD_BYTES (GUARD_ROWS*J_DIM)   // 393216

// conv GEMM tiling: 128(M) x 64(N) block, 4 waves (2x2), wave tile 64x32, BK=64
#define MB 128
#define NB 64
#define NST (K_TAP*(J_DIM/64))   // 100 K-steps (even)
#define BSET 12288                // bytes per LDS B-set: B0|B1|B2 each [64][64]

typedef __attribute__((ext_vector_type(4))) int   i32x4;

__device__ __forceinline__ void gl16(const void* g, void* l){ // async global->LDS, 16B/lane
  __builtin_amdgcn_global_load_lds((const __attribute__((address_space(1))) unsigned int*)g,
                                   (__attribute__((address_space(3))) unsigned int*)l, 16, 0, 0);
}

// ---------------------------------------------------------------------------
// 0a) zero guard region + BN integer-accumulator region (ws is poisoned)
// ---------------------------------------------------------------------------
__global__ void zero_guard_k(unsigned char* __restrict__ g, unsigned char* __restrict__ p){
  const int bid = blockIdx.x;
  if(bid < 96) *(uint4*)(g + (size_t)(bid*256 + threadIdx.x)*16) = (uint4){0,0,0,0};
  else         *(uint4*)(p + (size_t)((bid-96)*256 + threadIdx.x)*16) = (uint4){0,0,0,0};
}

// 0b) cast f32 binary input -> u8 spikes
__global__ void cast_u8_k(const float* __restrict__ x, unsigned char* __restrict__ s){
  const int i = blockIdx.x*256 + threadIdx.x;       // one float4 per thread
  const float4 v = *(const float4*)(x + (size_t)i*4);
  uchar4 o; o.x=(unsigned char)v.x; o.y=(unsigned char)v.y;
  o.z=(unsigned char)v.z; o.w=(unsigned char)v.w;
  *(uchar4*)(s + (size_t)i*4) = o;
}

// ---------------------------------------------------------------------------
// 1) DCLS gaussian kernel -> 23-bit fixed point, 3 signed-i8 digit planes.
//    kd[d][o][j] = W[o,j]*gnorm[o,j,k=24-d].  Per-column power-of-2 scale s_o;
//    q = rint(kd/s_o * 2^22); q = b2*2^16 + b1*2^8 + b0 exactly.
//    fsc[o] = s_o * 2^-22 (exact power of 2).
// ---------------------------------------------------------------------------
__global__ void build_kern_k(const float* __restrict__ W, const float* __restrict__ P,
                             signed char* __restrict__ k0, signed char* __restrict__ k1,
                             signed char* __restrict__ k2, float* __restrict__ fsc, int layer){
  __shared__ float red[256];
  const int o = blockIdx.x, j = threadIdx.x;
  const float w = W[(layer*H_DIM + o)*J_DIM + j];
  const float p = P[(layer*H_DIM + o)*J_DIM + j];
  const float c = p + 12.0f;              // P + K//2
  const float sg = 0.77f;                 // |0.5| + 0.27
  float v[K_TAP]; float ssum = 0.f;
#pragma unroll
  for(int k=0;k<K_TAP;k++){ float z = ((float)k - c)/sg; v[k] = expf(-0.5f*z*z); ssum += v[k]; }
  const float inv = 1.0f/(ssum + 1e-7f);
  float mv = 0.f;
#pragma unroll
  for(int k=0;k<K_TAP;k++){ v[k] = w * (v[k]*inv); mv = fmaxf(mv, fabsf(v[k])); }
  red[j] = mv; __syncthreads();
  for(int st=128; st; st>>=1){ if(j<st) red[j] = fmaxf(red[j], red[j+st]); __syncthreads(); }
  int e; frexpf(red[0], &e);              // maxv = f*2^e, f in [0.5,1)
  const float invq = ldexpf(1.f, 22 - e); // 2^22 / s_o
#pragma unroll
  for(int k=0;k<K_TAP;k++){
    const int d = (K_TAP-1)-k;
    int q = (int)lrintf(v[k]*invq);
    const int b0 = (int)(signed char)(q & 0xFF); q = (q - b0) >> 8;
    const int b1 = (int)(signed char)(q & 0xFF); q = (q - b1) >> 8;
    const size_t idx = (size_t)(d*H_DIM + o)*J_DIM + j;
    k0[idx] = (signed char)b0; k1[idx] = (signed char)b1; k2[idx] = (signed char)q;
  }
  if(j==0) fsc[o] = ldexpf(1.f, e - 22);
}

// ---------------------------------------------------------------------------
// 2) Delayed causal conv as EXACT i8 MFMA GEMM (3 digit planes, i32 acc).
//    128x64 block, 4 waves 2x2, wave tile 64x32, mfma_i32_16x16x64_i8, BK=64.
//    A (spikes) loaded DIRECTLY global->reg via plain C++ i32x4 loads
//    (compiler-tracked), depth-2 ping-pong afA/afB (static indices, #20).
//    B via gl16 into triple-buffered 12KB LDS sets (B-only LDS = 36KB).
//    T4 counted wait: per substep 7 VMEM ops issue (3 gl16 B + 4 A); at
//    substep-t entry, ops newer than B(t) = A(t)x4 + B(t+1)x3 + A(t+1)x4
//    = 11, so vmcnt(11) guarantees B(t) is in LDS. (Round-11 bug: vmcnt(3)
//    over-drained and exposed full load latency every step.) Compiler
//    inserts its own precise wait for A(t) before MFMA use. vmcnt(0) only
//    at the final step. One raw s_barrier per substep.
//    Epilogue: exact per-column integer BN sums (s1, s2 split hi/lo) via
//    shfl reduce + u64 atomics -> order-independent, bit-deterministic.
//    XCD swizzle (T1): n0-major chunks -> per-XCD L2-resident B panel.
// ---------------------------------------------------------------------------
__global__ __launch_bounds__(256,4) void conv_mfma_k(const unsigned char* __restrict__ spk,
    const signed char* __restrict__ k0, const signed char* __restrict__ k1,
    const signed char* __restrict__ k2, const float* __restrict__ fsc,
    float* __restrict__ y, long long* __restrict__ part){
  __shared__ unsigned char lds[3][BSET];  // per set: B0|B1|B2 each [64][64]
  const int tid = threadIdx.x, lane = tid & 63, wave = tid >> 6;
  // XCD-aware n0-major decode: xcd = bid%8 owns 128 consecutive q's
  const int bid = blockIdx.x;                      // 0..1023
  const int q   = (bid & 7)*128 + (bid >> 3);
  const int m0  = (q & 255) * MB;
  const int n0  = (q >> 8) * NB;
  const int wm0 = (wave >> 1) << 6;   // 0 / 64
  const int wn0 = (wave & 1) << 5;    // 0 / 32

  const int srow  = tid >> 2;                        // B staging row 0..63
  const int sslot = ((tid & 3) ^ (srow >> 1)) & 3;   // swizzled source 16B slot
  const int rslot = ((((lane>>4) ^ (lane>>1)) & 3) << 4);  // read slot byte off

  // A fragment global base: row = m0+wm0+(lane&15)+16*m, 16B k-chunk = lane>>4
  const unsigned char* abase = spk + (size_t)(m0 + wm0 + (lane&15) + GUARD_ROWS)*J_DIM
                               + ((lane>>4)<<4);

  i32x4 acc0[4][2], acc1[4][2], acc2[4][2];
#pragma unroll
  for(int m=0;m<4;m++)
#pragma unroll
    for(int n=0;n<2;n++){
      acc0[m][n] = (i32x4){0,0,0,0};
      acc1[m][n] = (i32x4){0,0,0,0};
      acc2[m][n] = (i32x4){0,0,0,0};
    }

  i32x4 afA[4], afB[4];

#define STAGE_B(base,t) do{ \
    const int d_ = (t)>>2, jc_ = ((t)&3)<<6; \
    unsigned char* lb_ = (base); \
    const size_t bo_ = (size_t)(d_*H_DIM + n0 + srow)*J_DIM + jc_ + sslot*16; \
    gl16(k0 + bo_, lb_        + wave*1024); \
    gl16(k1 + bo_, lb_ + 4096 + wave*1024); \
    gl16(k2 + bo_, lb_ + 8192 + wave*1024); \
  }while(0)

#define LOAD_A(AF,t) do{ \
    const int d_ = (t)>>2, jc_ = ((t)&3)<<6; \
    const unsigned char* a0_ = abase - (size_t)(d_<<6)*J_DIM + jc_; \
    AF[0] = *(const i32x4*)(a0_); \
    AF[1] = *(const i32x4*)(a0_ + 16*J_DIM); \
    AF[2] = *(const i32x4*)(a0_ + 32*J_DIM); \
    AF[3] = *(const i32x4*)(a0_ + 48*J_DIM); \
  }while(0)

#define SUBSTEP(t, AF) do{ \
    if((t) < NST-1) asm volatile("s_waitcnt vmcnt(11)" ::: "memory"); \
    else            asm volatile("s_waitcnt vmcnt(0)" ::: "memory"); \
    __builtin_amdgcn_s_barrier(); \
    __builtin_amdgcn_sched_barrier(0); \
    unsigned char* Lb = &lds[0][0] + rb*BSET; \
    if((t)+2 < NST){ int sb_ = rb + 2; if(sb_ >= 3) sb_ -= 3; STAGE_B(&lds[0][0] + sb_*BSET, (t)+2); } \
    i32x4 b0f[2], b1f[2], b2f[2]; \
    _Pragma("unroll") \
    for(int n=0;n<2;n++){ \
      const int ro = (wn0 + n*16 + (lane&15))*64 + rslot; \
      b0f[n] = *(const i32x4*)(Lb + ro); \
      b1f[n] = *(const i32x4*)(Lb + 4096 + ro); \
      b2f[n] = *(const i32x4*)(Lb + 8192 + ro); \
    } \
    __builtin_amdgcn_s_setprio(1); \
    _Pragma("unroll") \
    for(int m=0;m<4;m++) \
    _Pragma("unroll") \
      for(int n=0;n<2;n++){ \
        acc0[m][n] = __builtin_amdgcn_mfma_i32_16x16x64_i8(AF[m], b0f[n], acc0[m][n], 0,0,0); \
        acc1[m][n] = __builtin_amdgcn_mfma_i32_16x16x64_i8(AF[m], b1f[n], acc1[m][n], 0,0,0); \
        acc2[m][n] = __builtin_amdgcn_mfma_i32_16x16x64_i8(AF[m], b2f[n], acc2[m][n], 0,0,0); \
      } \
    __builtin_amdgcn_s_setprio(0); \
    if((t)+2 < NST) LOAD_A(AF, (t)+2); \
    rb += 1; if(rb == 3) rb = 0; \
  }while(0)

  // prologue: depth-2 prefetch (B sets 0,1; A reg slots afA, afB)
  STAGE_B(&lds[0][0], 0);
  LOAD_A(afA, 0);
  STAGE_B(&lds[0][0] + BSET, 1);
  LOAD_A(afB, 1);

  int rb = 0;
  for(int t=0; t<NST; t+=2){
    SUBSTEP(t,   afA);
    SUBSTEP(t+1, afB);
  }

  // epilogue: C/D mapping col=lane&15, row=(lane>>4)*4+r [shape-determined].
  // Exact int64 digit recombine; y-write; exact integer BN accumulation.
  const int r0 = m0 + wm0 + ((lane>>4)<<2);
  const int c0 = n0 + wn0 + (lane&15);
  const double f0 = (double)fsc[c0];
  const double f1 = (double)fsc[c0+16];
#pragma unroll
  for(int n=0;n<2;n++){
    const double fs = n ? f1 : f0;
    long long s1 = 0; unsigned long long shi = 0, slo = 0;
#pragma unroll
    for(int m=0;m<4;m++)
#pragma unroll
      for(int r=0;r<4;r++){
        const long long cmb = ((long long)acc2[m][n][r] << 16)
                            + ((long long)acc1[m][n][r] << 8)
                            +  (long long)acc0[m][n][r];
        y[(size_t)(r0 + m*16 + r)*H_DIM + c0 + n*16] = (float)((double)cmb * fs);
        s1 += cmb;
        const __int128 sq = (__int128)cmb * cmb;       // >= 0, < 2^70
        slo += (unsigned long long)(unsigned int)sq;   // low 32 bits
        shi += (unsigned long long)(sq >> 32);         // high bits (< 2^38)
      }
    s1  += __shfl_xor(s1, 16);  s1  += __shfl_xor(s1, 32);
    shi += __shfl_xor(shi, 16); shi += __shfl_xor(shi, 32);
    slo += __shfl_xor(slo, 16); slo += __shfl_xor(slo, 32);
    if(lane < 16){
      const int c = c0 + n*16;
      atomicAdd((unsigned long long*)&part[c],       (unsigned long long)s1);
      atomicAdd((unsigned long long*)&part[256 + c], shi);
      atomicAdd((unsigned long long*)&part[512 + c], slo);
    }
  }
#undef STAGE_B
#undef LOAD_A
#undef SUBSTEP
}

// ---------------------------------------------------------------------------
// 3) BN finalize from exact integer sums; re-zeros part for the next layer.
//    sum(y) = fs*s1 ; sum(y^2) = fs^2*(shi*2^32+slo) -- fs is a power of 2.
// ---------------------------------------------------------------------------
__global__ void bn_final_k(long long* __restrict__ part, const float* __restrict__ fsc,
                           float* __restrict__ sc, float* __restrict__ sh,
                           const float* __restrict__ gamma_, const float* __restrict__ bb_,
                           int layer){
  const int o = threadIdx.x;
  const long long s1           = part[o];
  const unsigned long long shi = (unsigned long long)part[256 + o];
  const unsigned long long slo = (unsigned long long)part[512 + o];
  part[o] = 0; part[256 + o] = 0; part[512 + o] = 0;   // ready for next layer
  const double fs  = (double)fsc[o];
  const double sy  = (double)s1 * fs;
  const double sy2 = ((double)shi * 4294967296.0 + (double)slo) * fs * fs;
  const double inv_n = 1.0 / (double)M_DIM;
  const double m   = sy * inv_n;
  const double var = sy2 * inv_n - m*m;      // biased, like jnp.var
  const double rs  = 1.0 / sqrt(var + (double)1e-5f);
  const float g  = gamma_[layer*H_DIM + o];
  const float bv = bb_[layer*H_DIM + o];
  const float scale = (float)((double)g * rs);
  sc[o] = scale;
  sh[o] = (float)((double)bv - m*(double)scale);
}

// ---------------------------------------------------------------------------
// 4) LIF soft-reset scan. One thread per (b,h), 16-deep prefetch.
//    TOUT=u8 inter-layer spikes, f32 final output (in-place on d_out).
//    NOTE: no __restrict__ on yin/sout — they alias for the final layer.
// ---------------------------------------------------------------------------
template<typename TOUT>
__global__ void lif_k(const float* yin, TOUT* sout,
                      const float* __restrict__ sc_, const float* __restrict__ sh_,
                      const float* __restrict__ beta_, const float* __restrict__ U0_,
                      int layer){
  const int idx = blockIdx.x*64 + threadIdx.x;   // 0..16383 = b*256+h
  const int h = idx & (H_DIM-1);
  const float scale = sc_[h];
  const float shift = sh_[h];
  const float beta  = beta_[layer*H_DIM + h];
  const float ombeta = 1.0f - beta;
  float U = U0_[layer*NBH + idx];
  float S = 0.f;
  float cur[16];
#pragma unroll
  for(int i=0;i<16;i++) cur[i] = yin[(size_t)i*NBH + idx];
  for(int t=0;t<T_DIM;t+=16){
    float nx[16];
#pragma unroll
    for(int i=0;i<16;i++){
      const int tt = t + 16 + i;
      nx[i] = (tt < T_DIM) ? yin[(size_t)tt*NBH + idx] : 0.f;
    }
#pragma unroll
    for(int i=0;i<16;i++){
      const float yv = fmaf(cur[i], scale, shift);
      U = beta*(U - S) + ombeta*yv;
      S = (U > 1.0f) ? 1.f : 0.f;              // (U - THETA) > 0
      sout[(size_t)(t+i)*NBH + idx] = (TOUT)S;
    }
#pragma unroll
    for(int i=0;i<16;i++) cur[i] = nx[i];
  }
}

// ---------------------------------------------------------------------------
// Launch. ws layout (13.7 MB):
//   spk  [0,          8,781,824)    guard(393216 zeros) + 32768*256 u8 spikes
//   k0   [8,781,824, 10,420,224)    25*256*256 i8 digit 0 (2^0)
//   k1   [10,420,224,12,058,624)    25*256*256 i8 digit 1 (2^8)
//   k2   [12,058,624,13,697,024)    25*256*256 i8 digit 2 (2^16)
//   fsc  [13,697,024,+1024)         256 f32 per-column scale
//   part [13,698,048,+8192)         3*256 i64 BN integer sums (+pad), zeroed
//   sc   [13,706,240,+1024) f32 ; sh [13,707,264,+1024) f32
// Conv y always lands in d_out (fully rewritten each layer before any read).
// ---------------------------------------------------------------------------
extern "C" void kernel_launch(void* const* d_in, const int* in_sizes, int n_in,
                              void* d_out, int out_size, void* d_ws, size_t ws_size,
                              hipStream_t stream){
  const float* x    = (const float*)d_in[0];
  const float* W    = (const float*)d_in[1];
  const float* P    = (const float*)d_in[2];
  const float* beta = (const float*)d_in[3];
  const float* gam  = (const float*)d_in[4];
  const float* bb   = (const float*)d_in[5];
  const float* U0   = (const float*)d_in[6];
  float* out = (float*)d_out;

  char* ws = (char*)d_ws;
  unsigned char* spk  = (unsigned char*)ws;                 // guarded base
  unsigned char* spkd = spk + GUARD_BYTES;                  // data region
  signed char*   k0   = (signed char*)(ws + 8781824);
  signed char*   k1   = (signed char*)(ws + 10420224);
  signed char*   k2   = (signed char*)(ws + 12058624);
  float*         fsc  = (float*)(ws + 13697024);
  long long*     part = (long long*)(ws + 13698048);
  float*         sc   = (float*)(ws + 13706240);
  float*         sh   = sc + 256;

  zero_guard_k<<<dim3(98), dim3(256), 0, stream>>>(spk, (unsigned char*)part);
  cast_u8_k<<<dim3((M_DIM*J_DIM)/1024), dim3(256), 0, stream>>>(x, spkd);

  for(int l=0;l<NL;l++){
    build_kern_k<<<dim3(H_DIM), dim3(J_DIM), 0, stream>>>(W, P, k0, k1, k2, fsc, l);
    conv_mfma_k<<<dim3((M_DIM/MB)*(H_DIM/NB)), dim3(256), 0, stream>>>(spk, k0, k1, k2, fsc, out, part);
    bn_final_k<<<dim3(1), dim3(H_DIM), 0, stream>>>(part, fsc, sc, sh, gam, bb, l);
    if(l < NL-1) lif_k<unsigned char><<<dim3(NBH/64), dim3(64), 0, stream>>>(out, spkd, sc, sh, beta, U0, l);
    else         lif_k<float>        <<<dim3(NBH/64), dim3(64), 0, stream>>>(out, out, sc, sh, beta, U0, l);
  }
}

// Round 13
// 817.302 us; speedup vs baseline: 4.7713x; 4.7713x over previous
//
#include <hip/hip_runtime.h>
#include <math.h>

// Model dims (fixed by the reference)
#define T_DIM 512
#define B_DIM 64
#define J_DIM 256
#define H_DIM 256
#define K_TAP 25
#define NL    3
#define M_DIM (T_DIM*B_DIM)   // 32768 rows = (t,b)
#define NBH   (B_DIM*H_DIM)   // 16384
#define GUARD_ROWS 1536                  // 64*24 zero rows before row 0
#define GUARD_BYTES (GUARD_ROWS*J_DIM)   // 393216

// conv GEMM tiling: 128(M) x 64(N) block, 4 waves (2x2), wave tile 64x32, BK=64
#define MB 128
#define NB 64
#define NST (K_TAP*(J_DIM/64))   // 100 K-steps (even)
#define BSET 12288                // bytes per LDS B-set: B0|B1|B2 each [64][64]

typedef __attribute__((ext_vector_type(4))) int   i32x4;

__device__ __forceinline__ void gl16(const void* g, void* l){ // async global->LDS, 16B/lane
  __builtin_amdgcn_global_load_lds((const __attribute__((address_space(1))) unsigned int*)g,
                                   (__attribute__((address_space(3))) unsigned int*)l, 16, 0, 0);
}

// ---------------------------------------------------------------------------
// 0a) zero guard region + BN integer-accumulator region (ws is poisoned)
// ---------------------------------------------------------------------------
__global__ void zero_guard_k(unsigned char* __restrict__ g, unsigned char* __restrict__ p){
  const int bid = blockIdx.x;
  if(bid < 96) *(uint4*)(g + (size_t)(bid*256 + threadIdx.x)*16) = (uint4){0,0,0,0};
  else         *(uint4*)(p + (size_t)((bid-96)*256 + threadIdx.x)*16) = (uint4){0,0,0,0};
}

// 0b) cast f32 binary input -> u8 spikes
__global__ void cast_u8_k(const float* __restrict__ x, unsigned char* __restrict__ s){
  const int i = blockIdx.x*256 + threadIdx.x;       // one float4 per thread
  const float4 v = *(const float4*)(x + (size_t)i*4);
  uchar4 o; o.x=(unsigned char)v.x; o.y=(unsigned char)v.y;
  o.z=(unsigned char)v.z; o.w=(unsigned char)v.w;
  *(uchar4*)(s + (size_t)i*4) = o;
}

// ---------------------------------------------------------------------------
// 1) DCLS gaussian kernel -> 23-bit fixed point, 3 signed-i8 digit planes.
//    kd[d][o][j] = W[o,j]*gnorm[o,j,k=24-d].  Per-column power-of-2 scale s_o;
//    q = rint(kd/s_o * 2^22); q = b2*2^16 + b1*2^8 + b0 exactly.
//    fsc[o] = s_o * 2^-22 (exact power of 2).
// ---------------------------------------------------------------------------
__global__ void build_kern_k(const float* __restrict__ W, const float* __restrict__ P,
                             signed char* __restrict__ k0, signed char* __restrict__ k1,
                             signed char* __restrict__ k2, float* __restrict__ fsc, int layer){
  __shared__ float red[256];
  const int o = blockIdx.x, j = threadIdx.x;
  const float w = W[(layer*H_DIM + o)*J_DIM + j];
  const float p = P[(layer*H_DIM + o)*J_DIM + j];
  const float c = p + 12.0f;              // P + K//2
  const float sg = 0.77f;                 // |0.5| + 0.27
  float v[K_TAP]; float ssum = 0.f;
#pragma unroll
  for(int k=0;k<K_TAP;k++){ float z = ((float)k - c)/sg; v[k] = expf(-0.5f*z*z); ssum += v[k]; }
  const float inv = 1.0f/(ssum + 1e-7f);
  float mv = 0.f;
#pragma unroll
  for(int k=0;k<K_TAP;k++){ v[k] = w * (v[k]*inv); mv = fmaxf(mv, fabsf(v[k])); }
  red[j] = mv; __syncthreads();
  for(int st=128; st; st>>=1){ if(j<st) red[j] = fmaxf(red[j], red[j+st]); __syncthreads(); }
  int e; frexpf(red[0], &e);              // maxv = f*2^e, f in [0.5,1)
  const float invq = ldexpf(1.f, 22 - e); // 2^22 / s_o
#pragma unroll
  for(int k=0;k<K_TAP;k++){
    const int d = (K_TAP-1)-k;
    int q = (int)lrintf(v[k]*invq);
    const int b0 = (int)(signed char)(q & 0xFF); q = (q - b0) >> 8;
    const int b1 = (int)(signed char)(q & 0xFF); q = (q - b1) >> 8;
    const size_t idx = (size_t)(d*H_DIM + o)*J_DIM + j;
    k0[idx] = (signed char)b0; k1[idx] = (signed char)b1; k2[idx] = (signed char)q;
  }
  if(j==0) fsc[o] = ldexpf(1.f, e - 22);
}

// ---------------------------------------------------------------------------
// 2) Delayed causal conv as EXACT i8 MFMA GEMM (3 digit planes, i32 acc).
//    128x64 block, 4 waves 2x2, wave tile 64x32, mfma_i32_16x16x64_i8, BK=64.
//    A (spikes) loaded DIRECTLY global->reg via plain C++ i32x4 loads
//    (compiler-tracked), depth-2 ping-pong afA/afB (static indices, #20).
//    B via gl16 into triple-buffered 12KB LDS sets (B-only LDS = 36KB).
//    T4 counted wait, ORDER-ROBUST: at substep-t entry, the only VMEM ops
//    newer than substep t-1's issue group are that group's 7 ops (3 gl16
//    B(t+1) + 4 A(t+1)), so vmcnt(7) guarantees everything from substep
//    t-2 -- including B(t) -- is retired, regardless of how the compiler
//    interleaves A-loads and gl16s WITHIN a substep. A(t) is also drained,
//    which costs nothing: this substep's MFMAs need it immediately anyway.
//    vmcnt(0) only at the final step. One raw s_barrier per substep.
//    __launch_bounds__(256,3): 84 VGPR fits without spilling (round-12
//    lesson: (256,4) forced VGPR=64 -> accumulator spill -> 2.7GB scratch).
//    Epilogue: exact per-column integer BN sums (s1, s2 split hi/lo) via
//    shfl reduce + u64 atomics -> order-independent, bit-deterministic.
//    XCD swizzle (T1): n0-major chunks -> per-XCD L2-resident B panel.
// ---------------------------------------------------------------------------
__global__ __launch_bounds__(256,3) void conv_mfma_k(const unsigned char* __restrict__ spk,
    const signed char* __restrict__ k0, const signed char* __restrict__ k1,
    const signed char* __restrict__ k2, const float* __restrict__ fsc,
    float* __restrict__ y, long long* __restrict__ part){
  __shared__ unsigned char lds[3][BSET];  // per set: B0|B1|B2 each [64][64]
  const int tid = threadIdx.x, lane = tid & 63, wave = tid >> 6;
  // XCD-aware n0-major decode: xcd = bid%8 owns 128 consecutive q's
  const int bid = blockIdx.x;                      // 0..1023
  const int q   = (bid & 7)*128 + (bid >> 3);
  const int m0  = (q & 255) * MB;
  const int n0  = (q >> 8) * NB;
  const int wm0 = (wave >> 1) << 6;   // 0 / 64
  const int wn0 = (wave & 1) << 5;    // 0 / 32

  const int srow  = tid >> 2;                        // B staging row 0..63
  const int sslot = ((tid & 3) ^ (srow >> 1)) & 3;   // swizzled source 16B slot
  const int rslot = ((((lane>>4) ^ (lane>>1)) & 3) << 4);  // read slot byte off

  // A fragment global base: row = m0+wm0+(lane&15)+16*m, 16B k-chunk = lane>>4
  const unsigned char* abase = spk + (size_t)(m0 + wm0 + (lane&15) + GUARD_ROWS)*J_DIM
                               + ((lane>>4)<<4);

  i32x4 acc0[4][2], acc1[4][2], acc2[4][2];
#pragma unroll
  for(int m=0;m<4;m++)
#pragma unroll
    for(int n=0;n<2;n++){
      acc0[m][n] = (i32x4){0,0,0,0};
      acc1[m][n] = (i32x4){0,0,0,0};
      acc2[m][n] = (i32x4){0,0,0,0};
    }

  i32x4 afA[4], afB[4];

#define STAGE_B(base,t) do{ \
    const int d_ = (t)>>2, jc_ = ((t)&3)<<6; \
    unsigned char* lb_ = (base); \
    const size_t bo_ = (size_t)(d_*H_DIM + n0 + srow)*J_DIM + jc_ + sslot*16; \
    gl16(k0 + bo_, lb_        + wave*1024); \
    gl16(k1 + bo_, lb_ + 4096 + wave*1024); \
    gl16(k2 + bo_, lb_ + 8192 + wave*1024); \
  }while(0)

#define LOAD_A(AF,t) do{ \
    const int d_ = (t)>>2, jc_ = ((t)&3)<<6; \
    const unsigned char* a0_ = abase - (size_t)(d_<<6)*J_DIM + jc_; \
    AF[0] = *(const i32x4*)(a0_); \
    AF[1] = *(const i32x4*)(a0_ + 16*J_DIM); \
    AF[2] = *(const i32x4*)(a0_ + 32*J_DIM); \
    AF[3] = *(const i32x4*)(a0_ + 48*J_DIM); \
  }while(0)

#define SUBSTEP(t, AF) do{ \
    if((t) < NST-1) asm volatile("s_waitcnt vmcnt(7)" ::: "memory"); \
    else            asm volatile("s_waitcnt vmcnt(0)" ::: "memory"); \
    __builtin_amdgcn_s_barrier(); \
    __builtin_amdgcn_sched_barrier(0); \
    unsigned char* Lb = &lds[0][0] + rb*BSET; \
    if((t)+2 < NST){ int sb_ = rb + 2; if(sb_ >= 3) sb_ -= 3; STAGE_B(&lds[0][0] + sb_*BSET, (t)+2); } \
    i32x4 b0f[2], b1f[2], b2f[2]; \
    _Pragma("unroll") \
    for(int n=0;n<2;n++){ \
      const int ro = (wn0 + n*16 + (lane&15))*64 + rslot; \
      b0f[n] = *(const i32x4*)(Lb + ro); \
      b1f[n] = *(const i32x4*)(Lb + 4096 + ro); \
      b2f[n] = *(const i32x4*)(Lb + 8192 + ro); \
    } \
    __builtin_amdgcn_s_setprio(1); \
    _Pragma("unroll") \
    for(int m=0;m<4;m++) \
    _Pragma("unroll") \
      for(int n=0;n<2;n++){ \
        acc0[m][n] = __builtin_amdgcn_mfma_i32_16x16x64_i8(AF[m], b0f[n], acc0[m][n], 0,0,0); \
        acc1[m][n] = __builtin_amdgcn_mfma_i32_16x16x64_i8(AF[m], b1f[n], acc1[m][n], 0,0,0); \
        acc2[m][n] = __builtin_amdgcn_mfma_i32_16x16x64_i8(AF[m], b2f[n], acc2[m][n], 0,0,0); \
      } \
    __builtin_amdgcn_s_setprio(0); \
    if((t)+2 < NST) LOAD_A(AF, (t)+2); \
    rb += 1; if(rb == 3) rb = 0; \
  }while(0)

  // prologue: depth-2 prefetch (B sets 0,1; A reg slots afA, afB)
  STAGE_B(&lds[0][0], 0);
  LOAD_A(afA, 0);
  STAGE_B(&lds[0][0] + BSET, 1);
  LOAD_A(afB, 1);

  int rb = 0;
  for(int t=0; t<NST; t+=2){
    SUBSTEP(t,   afA);
    SUBSTEP(t+1, afB);
  }

  // epilogue: C/D mapping col=lane&15, row=(lane>>4)*4+r [shape-determined].
  // Exact int64 digit recombine; y-write; exact integer BN accumulation.
  const int r0 = m0 + wm0 + ((lane>>4)<<2);
  const int c0 = n0 + wn0 + (lane&15);
  const double f0 = (double)fsc[c0];
  const double f1 = (double)fsc[c0+16];
#pragma unroll
  for(int n=0;n<2;n++){
    const double fs = n ? f1 : f0;
    long long s1 = 0; unsigned long long shi = 0, slo = 0;
#pragma unroll
    for(int m=0;m<4;m++)
#pragma unroll
      for(int r=0;r<4;r++){
        const long long cmb = ((long long)acc2[m][n][r] << 16)
                            + ((long long)acc1[m][n][r] << 8)
                            +  (long long)acc0[m][n][r];
        y[(size_t)(r0 + m*16 + r)*H_DIM + c0 + n*16] = (float)((double)cmb * fs);
        s1 += cmb;
        const __int128 sq = (__int128)cmb * cmb;       // >= 0, < 2^70
        slo += (unsigned long long)(unsigned int)sq;   // low 32 bits
        shi += (unsigned long long)(sq >> 32);         // high bits (< 2^38)
      }
    s1  += __shfl_xor(s1, 16);  s1  += __shfl_xor(s1, 32);
    shi += __shfl_xor(shi, 16); shi += __shfl_xor(shi, 32);
    slo += __shfl_xor(slo, 16); slo += __shfl_xor(slo, 32);
    if(lane < 16){
      const int c = c0 + n*16;
      atomicAdd((unsigned long long*)&part[c],       (unsigned long long)s1);
      atomicAdd((unsigned long long*)&part[256 + c], shi);
      atomicAdd((unsigned long long*)&part[512 + c], slo);
    }
  }
#undef STAGE_B
#undef LOAD_A
#undef SUBSTEP
}

// ---------------------------------------------------------------------------
// 3) BN finalize from exact integer sums; re-zeros part for the next layer.
//    sum(y) = fs*s1 ; sum(y^2) = fs^2*(shi*2^32+slo) -- fs is a power of 2.
// ---------------------------------------------------------------------------
__global__ void bn_final_k(long long* __restrict__ part, const float* __restrict__ fsc,
                           float* __restrict__ sc, float* __restrict__ sh,
                           const float* __restrict__ gamma_, const float* __restrict__ bb_,
                           int layer){
  const int o = threadIdx.x;
  const long long s1           = part[o];
  const unsigned long long shi = (unsigned long long)part[256 + o];
  const unsigned long long slo = (unsigned long long)part[512 + o];
  part[o] = 0; part[256 + o] = 0; part[512 + o] = 0;   // ready for next layer
  const double fs  = (double)fsc[o];
  const double sy  = (double)s1 * fs;
  const double sy2 = ((double)shi * 4294967296.0 + (double)slo) * fs * fs;
  const double inv_n = 1.0 / (double)M_DIM;
  const double m   = sy * inv_n;
  const double var = sy2 * inv_n - m*m;      // biased, like jnp.var
  const double rs  = 1.0 / sqrt(var + (double)1e-5f);
  const float g  = gamma_[layer*H_DIM + o];
  const float bv = bb_[layer*H_DIM + o];
  const float scale = (float)((double)g * rs);
  sc[o] = scale;
  sh[o] = (float)((double)bv - m*(double)scale);
}

// ---------------------------------------------------------------------------
// 4) LIF soft-reset scan. One thread per (b,h), 16-deep prefetch.
//    TOUT=u8 inter-layer spikes, f32 final output (in-place on d_out).
//    NOTE: no __restrict__ on yin/sout — they alias for the final layer.
// ---------------------------------------------------------------------------
template<typename TOUT>
__global__ void lif_k(const float* yin, TOUT* sout,
                      const float* __restrict__ sc_, const float* __restrict__ sh_,
                      const float* __restrict__ beta_, const float* __restrict__ U0_,
                      int layer){
  const int idx = blockIdx.x*64 + threadIdx.x;   // 0..16383 = b*256+h
  const int h = idx & (H_DIM-1);
  const float scale = sc_[h];
  const float shift = sh_[h];
  const float beta  = beta_[layer*H_DIM + h];
  const float ombeta = 1.0f - beta;
  float U = U0_[layer*NBH + idx];
  float S = 0.f;
  float cur[16];
#pragma unroll
  for(int i=0;i<16;i++) cur[i] = yin[(size_t)i*NBH + idx];
  for(int t=0;t<T_DIM;t+=16){
    float nx[16];
#pragma unroll
    for(int i=0;i<16;i++){
      const int tt = t + 16 + i;
      nx[i] = (tt < T_DIM) ? yin[(size_t)tt*NBH + idx] : 0.f;
    }
#pragma unroll
    for(int i=0;i<16;i++){
      const float yv = fmaf(cur[i], scale, shift);
      U = beta*(U - S) + ombeta*yv;
      S = (U > 1.0f) ? 1.f : 0.f;              // (U - THETA) > 0
      sout[(size_t)(t+i)*NBH + idx] = (TOUT)S;
    }
#pragma unroll
    for(int i=0;i<16;i++) cur[i] = nx[i];
  }
}

// ---------------------------------------------------------------------------
// Launch. ws layout (13.7 MB):
//   spk  [0,          8,781,824)    guard(393216 zeros) + 32768*256 u8 spikes
//   k0   [8,781,824, 10,420,224)    25*256*256 i8 digit 0 (2^0)
//   k1   [10,420,224,12,058,624)    25*256*256 i8 digit 1 (2^8)
//   k2   [12,058,624,13,697,024)    25*256*256 i8 digit 2 (2^16)
//   fsc  [13,697,024,+1024)         256 f32 per-column scale
//   part [13,698,048,+8192)         3*256 i64 BN integer sums (+pad), zeroed
//   sc   [13,706,240,+1024) f32 ; sh [13,707,264,+1024) f32
// Conv y always lands in d_out (fully rewritten each layer before any read).
// ---------------------------------------------------------------------------
extern "C" void kernel_launch(void* const* d_in, const int* in_sizes, int n_in,
                              void* d_out, int out_size, void* d_ws, size_t ws_size,
                              hipStream_t stream){
  const float* x    = (const float*)d_in[0];
  const float* W    = (const float*)d_in[1];
  const float* P    = (const float*)d_in[2];
  const float* beta = (const float*)d_in[3];
  const float* gam  = (const float*)d_in[4];
  const float* bb   = (const float*)d_in[5];
  const float* U0   = (const float*)d_in[6];
  float* out = (float*)d_out;

  char* ws = (char*)d_ws;
  unsigned char* spk  = (unsigned char*)ws;                 // guarded base
  unsigned char* spkd = spk + GUARD_BYTES;                  // data region
  signed char*   k0   = (signed char*)(ws + 8781824);
  signed char*   k1   = (signed char*)(ws + 10420224);
  signed char*   k2   = (signed char*)(ws + 12058624);
  float*         fsc  = (float*)(ws + 13697024);
  long long*     part = (long long*)(ws + 13698048);
  float*         sc   = (float*)(ws + 13706240);
  float*         sh   = sc + 256;

  zero_guard_k<<<dim3(98), dim3(256), 0, stream>>>(spk, (unsigned char*)part);
  cast_u8_k<<<dim3((M_DIM*J_DIM)/1024), dim3(256), 0, stream>>>(x, spkd);

  for(int l=0;l<NL;l++){
    build_kern_k<<<dim3(H_DIM), dim3(J_DIM), 0, stream>>>(W, P, k0, k1, k2, fsc, l);
    conv_mfma_k<<<dim3((M_DIM/MB)*(H_DIM/NB)), dim3(256), 0, stream>>>(spk, k0, k1, k2, fsc, out, part);
    bn_final_k<<<dim3(1), dim3(H_DIM), 0, stream>>>(part, fsc, sc, sh, gam, bb, l);
    if(l < NL-1) lif_k<unsigned char><<<dim3(NBH/64), dim3(64), 0, stream>>>(out, spkd, sc, sh, beta, U0, l);
    else         lif_k<float>        <<<dim3(NBH/64), dim3(64), 0, stream>>>(out, out, sc, sh, beta, U0, l);
  }
}

// Round 14
// 543.964 us; speedup vs baseline: 7.1689x; 1.5025x over previous
//
#include <hip/hip_runtime.h>
#include <math.h>

// Model dims (fixed by the reference)
#define T_DIM 512
#define B_DIM 64
#define J_DIM 256
#define H_DIM 256
#define K_TAP 25
#define NL    3
#define M_DIM (T_DIM*B_DIM)   // 32768 rows = (t,b)
#define NBH   (B_DIM*H_DIM)   // 16384
#define GUARD_ROWS 1536                  // 64*24 zero rows before row 0
#define GUARD_BYTES (GUARD_ROWS*J_DIM)   // 393216

// conv GEMM tiling: 128(M) x 64(N) block, 4 waves (2x2), wave tile 64x32, BK=64
#define MB 128
#define NB 64
#define NST (K_TAP*(J_DIM/64))   // 100 K-steps
#define BSET 20480                // bytes per LDS set: A[128][64] | B0|B1|B2 [64][64]

typedef __attribute__((ext_vector_type(4))) int   i32x4;

__device__ __forceinline__ void gl16(const void* g, void* l){ // async global->LDS, 16B/lane
  __builtin_amdgcn_global_load_lds((const __attribute__((address_space(1))) unsigned int*)g,
                                   (__attribute__((address_space(3))) unsigned int*)l, 16, 0, 0);
}

// ---------------------------------------------------------------------------
// 0a) zero guard region + BN integer-accumulator region (ws is poisoned)
// ---------------------------------------------------------------------------
__global__ void zero_guard_k(unsigned char* __restrict__ g, unsigned char* __restrict__ p){
  const int bid = blockIdx.x;
  if(bid < 96) *(uint4*)(g + (size_t)(bid*256 + threadIdx.x)*16) = (uint4){0,0,0,0};
  else         *(uint4*)(p + (size_t)((bid-96)*256 + threadIdx.x)*16) = (uint4){0,0,0,0};
}

// 0b) cast f32 binary input -> u8 spikes
__global__ void cast_u8_k(const float* __restrict__ x, unsigned char* __restrict__ s){
  const int i = blockIdx.x*256 + threadIdx.x;       // one float4 per thread
  const float4 v = *(const float4*)(x + (size_t)i*4);
  uchar4 o; o.x=(unsigned char)v.x; o.y=(unsigned char)v.y;
  o.z=(unsigned char)v.z; o.w=(unsigned char)v.w;
  *(uchar4*)(s + (size_t)i*4) = o;
}

// ---------------------------------------------------------------------------
// 1) DCLS gaussian kernel -> 23-bit fixed point, 3 signed-i8 digit planes.
//    kd[d][o][j] = W[o,j]*gnorm[o,j,k=24-d].  Per-column power-of-2 scale s_o;
//    q = rint(kd/s_o * 2^22); q = b2*2^16 + b1*2^8 + b0 exactly.
//    fsc[o] = s_o * 2^-22 (exact power of 2).
// ---------------------------------------------------------------------------
__global__ void build_kern_k(const float* __restrict__ W, const float* __restrict__ P,
                             signed char* __restrict__ k0, signed char* __restrict__ k1,
                             signed char* __restrict__ k2, float* __restrict__ fsc, int layer){
  __shared__ float red[256];
  const int o = blockIdx.x, j = threadIdx.x;
  const float w = W[(layer*H_DIM + o)*J_DIM + j];
  const float p = P[(layer*H_DIM + o)*J_DIM + j];
  const float c = p + 12.0f;              // P + K//2
  const float sg = 0.77f;                 // |0.5| + 0.27
  float v[K_TAP]; float ssum = 0.f;
#pragma unroll
  for(int k=0;k<K_TAP;k++){ float z = ((float)k - c)/sg; v[k] = expf(-0.5f*z*z); ssum += v[k]; }
  const float inv = 1.0f/(ssum + 1e-7f);
  float mv = 0.f;
#pragma unroll
  for(int k=0;k<K_TAP;k++){ v[k] = w * (v[k]*inv); mv = fmaxf(mv, fabsf(v[k])); }
  red[j] = mv; __syncthreads();
  for(int st=128; st; st>>=1){ if(j<st) red[j] = fmaxf(red[j], red[j+st]); __syncthreads(); }
  int e; frexpf(red[0], &e);              // maxv = f*2^e, f in [0.5,1)
  const float invq = ldexpf(1.f, 22 - e); // 2^22 / s_o
#pragma unroll
  for(int k=0;k<K_TAP;k++){
    const int d = (K_TAP-1)-k;
    int q = (int)lrintf(v[k]*invq);
    const int b0 = (int)(signed char)(q & 0xFF); q = (q - b0) >> 8;
    const int b1 = (int)(signed char)(q & 0xFF); q = (q - b1) >> 8;
    const size_t idx = (size_t)(d*H_DIM + o)*J_DIM + j;
    k0[idx] = (signed char)b0; k1[idx] = (signed char)b1; k2[idx] = (signed char)q;
  }
  if(j==0) fsc[o] = ldexpf(1.f, e - 22);
}

// ---------------------------------------------------------------------------
// 2) Delayed causal conv as EXACT i8 MFMA GEMM (3 digit planes, i32 acc).
//    ROUND-8 PROVEN LOOP (152 us/layer): A (u8 spikes) AND B (i8 digits)
//    both staged by gl16 into TRIPLE-buffered 20KB LDS sets; counted
//    vmcnt(5) (5 gl16/step in a single FIFO; at step-t entry only set(t+1)'s
//    5 are newer than set(t) -> set(t) landed); vmcnt(0) only at the final
//    step; ONE raw s_barrier per step; setprio around the MFMA cluster.
//    Conflict-free LDS via source-slot swizzle (m173): phys slot p of row r
//    holds logical slot p^((r>>1)&3); read slot ((lane>>4)^(lane>>1))&3.
//    XCD swizzle (T1): n0-major chunks -> per-XCD L2-resident B panel.
//    NEW vs round 8: fused exact-integer BN epilogue (deletes bn_stats_k's
//    33.5MB re-read): per-column s1=SUM(cmb), s2=SUM(cmb^2) split hi/lo,
//    shfl-reduced, one u64 atomic per column -> order-independent,
//    bit-deterministic.
// ---------------------------------------------------------------------------
__global__ __launch_bounds__(256,2) void conv_mfma_k(const unsigned char* __restrict__ spk,
    const signed char* __restrict__ k0, const signed char* __restrict__ k1,
    const signed char* __restrict__ k2, const float* __restrict__ fsc,
    float* __restrict__ y, long long* __restrict__ part){
  __shared__ unsigned char lds[3][BSET];  // per set: A[128][64] | B0|B1|B2 [64][64]
  const int tid = threadIdx.x, lane = tid & 63, wave = tid >> 6;
  // XCD-aware n0-major decode: xcd = bid%8 owns 128 consecutive q's
  const int bid = blockIdx.x;                      // 0..1023
  const int q   = (bid & 7)*128 + (bid >> 3);
  const int m0  = (q & 255) * MB;
  const int n0  = (q >> 8) * NB;
  const int wm0 = (wave >> 1) << 6;   // 0 / 64
  const int wn0 = (wave & 1) << 5;    // 0 / 32

  const int srow  = tid >> 2;                        // staging row 0..63
  const int sslot = ((tid & 3) ^ (srow >> 1)) & 3;   // swizzled source 16B slot
  const int rslot = ((((lane>>4) ^ (lane>>1)) & 3) << 4);  // read slot byte off

  i32x4 acc0[4][2], acc1[4][2], acc2[4][2];
#pragma unroll
  for(int m=0;m<4;m++)
#pragma unroll
    for(int n=0;n<2;n++){
      acc0[m][n] = (i32x4){0,0,0,0};
      acc1[m][n] = (i32x4){0,0,0,0};
      acc2[m][n] = (i32x4){0,0,0,0};
    }

#define STAGE(base,t) do{ \
    const int d_ = (t)>>2, jc_ = ((t)&3)<<6; \
    unsigned char* lb_ = (base); \
    const unsigned char* as_ = spk + (size_t)(m0 + srow - (d_<<6) + GUARD_ROWS)*J_DIM + jc_ + sslot*16; \
    gl16(as_,                    lb_        + wave*1024); \
    gl16(as_ + (size_t)64*J_DIM, lb_ + 4096 + wave*1024); \
    const size_t bo_ = (size_t)(d_*H_DIM + n0 + srow)*J_DIM + jc_ + sslot*16; \
    gl16(k0 + bo_, lb_ + 8192  + wave*1024); \
    gl16(k1 + bo_, lb_ + 12288 + wave*1024); \
    gl16(k2 + bo_, lb_ + 16384 + wave*1024); \
  }while(0)

  unsigned char* const L = &lds[0][0];

  // prologue: stage t=0 -> set0, t=1 -> set1 (depth-2 prefetch)
  STAGE(L, 0);
  STAGE(L + BSET, 1);

  int rb = 0;   // read set for iter t (t % 3)
  for(int t=0; t<NST; ++t){
    if(t < NST-1) asm volatile("s_waitcnt vmcnt(5)" ::: "memory");  // set(t) landed
    else          asm volatile("s_waitcnt vmcnt(0)" ::: "memory");  // final drain
    __builtin_amdgcn_s_barrier();
    __builtin_amdgcn_sched_barrier(0);
    unsigned char* Lb = L + rb*BSET;
    i32x4 af[4], b0f[2], b1f[2], b2f[2];
#pragma unroll
    for(int m=0;m<4;m++)
      af[m] = *(const i32x4*)(Lb + (wm0 + m*16 + (lane&15))*64 + rslot);
#pragma unroll
    for(int n=0;n<2;n++){
      const int ro = (wn0 + n*16 + (lane&15))*64 + rslot;
      b0f[n] = *(const i32x4*)(Lb + 8192  + ro);
      b1f[n] = *(const i32x4*)(Lb + 12288 + ro);
      b2f[n] = *(const i32x4*)(Lb + 16384 + ro);
    }
    if(t+2 < NST){
      int sb = rb + 2; if(sb >= 3) sb -= 3;
      STAGE(L + sb*BSET, t+2);          // issue early (T14); lands by iter t+2
    }
    __builtin_amdgcn_s_setprio(1);
#pragma unroll
    for(int m=0;m<4;m++)
#pragma unroll
      for(int n=0;n<2;n++){
        acc0[m][n] = __builtin_amdgcn_mfma_i32_16x16x64_i8(af[m], b0f[n], acc0[m][n], 0,0,0);
        acc1[m][n] = __builtin_amdgcn_mfma_i32_16x16x64_i8(af[m], b1f[n], acc1[m][n], 0,0,0);
        acc2[m][n] = __builtin_amdgcn_mfma_i32_16x16x64_i8(af[m], b2f[n], acc2[m][n], 0,0,0);
      }
    __builtin_amdgcn_s_setprio(0);
    rb += 1; if(rb == 3) rb = 0;
  }

  // epilogue: C/D mapping col=lane&15, row=(lane>>4)*4+r [shape-determined].
  // Exact int64 digit recombine; y-write; exact integer BN accumulation.
  const int r0 = m0 + wm0 + ((lane>>4)<<2);
  const int c0 = n0 + wn0 + (lane&15);
  const double f0 = (double)fsc[c0];
  const double f1 = (double)fsc[c0+16];
#pragma unroll
  for(int n=0;n<2;n++){
    const double fs = n ? f1 : f0;
    long long s1 = 0; unsigned long long shi = 0, slo = 0;
#pragma unroll
    for(int m=0;m<4;m++)
#pragma unroll
      for(int r=0;r<4;r++){
        const long long cmb = ((long long)acc2[m][n][r] << 16)
                            + ((long long)acc1[m][n][r] << 8)
                            +  (long long)acc0[m][n][r];
        y[(size_t)(r0 + m*16 + r)*H_DIM + c0 + n*16] = (float)((double)cmb * fs);
        s1 += cmb;
        const __int128 sq = (__int128)cmb * cmb;       // >= 0, < 2^70
        slo += (unsigned long long)(unsigned int)sq;   // low 32 bits
        shi += (unsigned long long)(sq >> 32);         // high bits (< 2^38)
      }
    s1  += __shfl_xor(s1, 16);  s1  += __shfl_xor(s1, 32);
    shi += __shfl_xor(shi, 16); shi += __shfl_xor(shi, 32);
    slo += __shfl_xor(slo, 16); slo += __shfl_xor(slo, 32);
    if(lane < 16){
      const int c = c0 + n*16;
      atomicAdd((unsigned long long*)&part[c],       (unsigned long long)s1);
      atomicAdd((unsigned long long*)&part[256 + c], shi);
      atomicAdd((unsigned long long*)&part[512 + c], slo);
    }
  }
#undef STAGE
}

// ---------------------------------------------------------------------------
// 3) BN finalize from exact integer sums; re-zeros part for the next layer.
//    sum(y) = fs*s1 ; sum(y^2) = fs^2*(shi*2^32+slo) -- fs is a power of 2.
// ---------------------------------------------------------------------------
__global__ void bn_final_k(long long* __restrict__ part, const float* __restrict__ fsc,
                           float* __restrict__ sc, float* __restrict__ sh,
                           const float* __restrict__ gamma_, const float* __restrict__ bb_,
                           int layer){
  const int o = threadIdx.x;
  const long long s1           = part[o];
  const unsigned long long shi = (unsigned long long)part[256 + o];
  const unsigned long long slo = (unsigned long long)part[512 + o];
  part[o] = 0; part[256 + o] = 0; part[512 + o] = 0;   // ready for next layer
  const double fs  = (double)fsc[o];
  const double sy  = (double)s1 * fs;
  const double sy2 = ((double)shi * 4294967296.0 + (double)slo) * fs * fs;
  const double inv_n = 1.0 / (double)M_DIM;
  const double m   = sy * inv_n;
  const double var = sy2 * inv_n - m*m;      // biased, like jnp.var
  const double rs  = 1.0 / sqrt(var + (double)1e-5f);
  const float g  = gamma_[layer*H_DIM + o];
  const float bv = bb_[layer*H_DIM + o];
  const float scale = (float)((double)g * rs);
  sc[o] = scale;
  sh[o] = (float)((double)bv - m*(double)scale);
}

// ---------------------------------------------------------------------------
// 4) LIF soft-reset scan. One thread per (b,h), 16-deep prefetch.
//    TOUT=u8 inter-layer spikes, f32 final output (in-place on d_out).
//    NOTE: no __restrict__ on yin/sout — they alias for the final layer.
// ---------------------------------------------------------------------------
template<typename TOUT>
__global__ void lif_k(const float* yin, TOUT* sout,
                      const float* __restrict__ sc_, const float* __restrict__ sh_,
                      const float* __restrict__ beta_, const float* __restrict__ U0_,
                      int layer){
  const int idx = blockIdx.x*64 + threadIdx.x;   // 0..16383 = b*256+h
  const int h = idx & (H_DIM-1);
  const float scale = sc_[h];
  const float shift = sh_[h];
  const float beta  = beta_[layer*H_DIM + h];
  const float ombeta = 1.0f - beta;
  float U = U0_[layer*NBH + idx];
  float S = 0.f;
  float cur[16];
#pragma unroll
  for(int i=0;i<16;i++) cur[i] = yin[(size_t)i*NBH + idx];
  for(int t=0;t<T_DIM;t+=16){
    float nx[16];
#pragma unroll
    for(int i=0;i<16;i++){
      const int tt = t + 16 + i;
      nx[i] = (tt < T_DIM) ? yin[(size_t)tt*NBH + idx] : 0.f;
    }
#pragma unroll
    for(int i=0;i<16;i++){
      const float yv = fmaf(cur[i], scale, shift);
      U = beta*(U - S) + ombeta*yv;
      S = (U > 1.0f) ? 1.f : 0.f;              // (U - THETA) > 0
      sout[(size_t)(t+i)*NBH + idx] = (TOUT)S;
    }
#pragma unroll
    for(int i=0;i<16;i++) cur[i] = nx[i];
  }
}

// ---------------------------------------------------------------------------
// Launch. ws layout (13.7 MB):
//   spk  [0,          8,781,824)    guard(393216 zeros) + 32768*256 u8 spikes
//   k0   [8,781,824, 10,420,224)    25*256*256 i8 digit 0 (2^0)
//   k1   [10,420,224,12,058,624)    25*256*256 i8 digit 1 (2^8)
//   k2   [12,058,624,13,697,024)    25*256*256 i8 digit 2 (2^16)
//   fsc  [13,697,024,+1024)         256 f32 per-column scale
//   part [13,698,048,+8192)         3*256 i64 BN integer sums (+pad), zeroed
//   sc   [13,706,240,+1024) f32 ; sh [13,707,264,+1024) f32
// Conv y always lands in d_out (fully rewritten each layer before any read).
// ---------------------------------------------------------------------------
extern "C" void kernel_launch(void* const* d_in, const int* in_sizes, int n_in,
                              void* d_out, int out_size, void* d_ws, size_t ws_size,
                              hipStream_t stream){
  const float* x    = (const float*)d_in[0];
  const float* W    = (const float*)d_in[1];
  const float* P    = (const float*)d_in[2];
  const float* beta = (const float*)d_in[3];
  const float* gam  = (const float*)d_in[4];
  const float* bb   = (const float*)d_in[5];
  const float* U0   = (const float*)d_in[6];
  float* out = (float*)d_out;

  char* ws = (char*)d_ws;
  unsigned char* spk  = (unsigned char*)ws;                 // guarded base
  unsigned char* spkd = spk + GUARD_BYTES;                  // data region
  signed char*   k0   = (signed char*)(ws + 8781824);
  signed char*   k1   = (signed char*)(ws + 10420224);
  signed char*   k2   = (signed char*)(ws + 12058624);
  float*         fsc  = (float*)(ws + 13697024);
  long long*     part = (long long*)(ws + 13698048);
  float*         sc   = (float*)(ws + 13706240);
  float*         sh   = sc + 256;

  zero_guard_k<<<dim3(98), dim3(256), 0, stream>>>(spk, (unsigned char*)part);
  cast_u8_k<<<dim3((M_DIM*J_DIM)/1024), dim3(256), 0, stream>>>(x, spkd);

  for(int l=0;l<NL;l++){
    build_kern_k<<<dim3(H_DIM), dim3(J_DIM), 0, stream>>>(W, P, k0, k1, k2, fsc, l);
    conv_mfma_k<<<dim3((M_DIM/MB)*(H_DIM/NB)), dim3(256), 0, stream>>>(spk, k0, k1, k2, fsc, out, part);
    bn_final_k<<<dim3(1), dim3(H_DIM), 0, stream>>>(part, fsc, sc, sh, gam, bb, l);
    if(l < NL-1) lif_k<unsigned char><<<dim3(NBH/64), dim3(64), 0, stream>>>(out, spkd, sc, sh, beta, U0, l);
    else         lif_k<float>        <<<dim3(NBH/64), dim3(64), 0, stream>>>(out, out, sc, sh, beta, U0, l);
  }
}